// Round 8
// baseline (318.101 us; speedup 1.0000x reference)
//
#include <hip/hip_runtime.h>
#include <hip/hip_bf16.h>

// Problem constants
#define CC 256      // channels
#define CKD 32      // q/k projection dim
#define NN 4096     // H*W
#define HH 64
#define WW 64
#define BB 4

#define LOG2E 1.44269504088896f
#define EXPSHIFT 23.0831203874f   // 16 * LOG2E

typedef __attribute__((ext_vector_type(8))) short short8;   // 8 bf16 (4 VGPRs)
typedef __attribute__((ext_vector_type(4))) float floatx4;  // MFMA C/D frag

__device__ __forceinline__ unsigned f2bf(float f) {
  union { float f; unsigned u; } v; v.f = f;
  unsigned r = v.u + 0x7fffu + ((v.u >> 16) & 1u);   // RNE
  return r >> 16;
}
__device__ __forceinline__ float fast_exp2(float x) {
#if __has_builtin(__builtin_amdgcn_exp2f)
  return __builtin_amdgcn_exp2f(x);
#else
  return __expf(x * 0.693147181f);
#endif
}
__device__ __forceinline__ float bf_lo(unsigned u) { return __uint_as_float(u << 16); }
__device__ __forceinline__ float bf_hi(unsigned u) { return __uint_as_float(u & 0xffff0000u); }

// LDS-only barrier: orders DS ops across waves WITHOUT draining vmcnt.
__device__ __forceinline__ void bar_lds() {
  asm volatile("s_waitcnt lgkmcnt(0)" ::: "memory");
  __builtin_amdgcn_s_barrier();
}

// ---------------------------------------------------------------------------
// Kernel 0: merged pack. z<8: pack x (fp32 [img][c][n]) -> Xp (bf16 [img][n][c]).
// z==8: pack conv weights Wp[tap][o][c] (tap 9 = 1x1), QKV weights
// Wqkv[inp][o=320][c] (q rows scaled by log2e), Bias[inp][320] (fp32).
// ---------------------------------------------------------------------------
__global__ __launch_bounds__(256) void pack_kernel(
    const float* __restrict__ x1, const float* __restrict__ x2,
    unsigned short* __restrict__ Xp,
    const float* __restrict__ wd1, const float* __restrict__ wd3,
    const float* __restrict__ wq1, const float* __restrict__ wk1,
    const float* __restrict__ wv1,
    const float* __restrict__ wq2, const float* __restrict__ wk2,
    const float* __restrict__ wv2,
    const float* __restrict__ bq1, const float* __restrict__ bk1,
    const float* __restrict__ bv1,
    const float* __restrict__ bq2, const float* __restrict__ bk2,
    const float* __restrict__ bv2,
    unsigned short* __restrict__ Wp, unsigned short* __restrict__ Wqkv,
    float* __restrict__ Bias) {
  const int t = threadIdx.x;
  __shared__ float tile[64][65];
  if (blockIdx.z < 8) {
    // ---- xpack ----
    const int nb = blockIdx.x, cbk = blockIdx.y, img = blockIdx.z;
    const float* X = ((img >> 2) ? x2 : x1) + (size_t)(img & 3) * CC * NN;
    const int n0 = nb * 64, c0 = cbk * 64;
    const int nl = t & 63, cl0 = t >> 6;
#pragma unroll
    for (int i = 0; i < 16; ++i)
      tile[cl0 + i * 4][nl] = X[(size_t)(c0 + cl0 + i * 4) * NN + n0 + nl];
    __syncthreads();
#pragma unroll
    for (int it = 0; it < 2; ++it) {
      int id = it * 256 + t;
      int nl2 = id >> 3, cc = id & 7;
      short8 v;
#pragma unroll
      for (int j = 0; j < 8; ++j) v[j] = (short)f2bf(tile[cc * 8 + j][nl2]);
      *(short8*)(Xp + (size_t)img * NN * CC + (size_t)(n0 + nl2) * CC + c0 + cc * 8) = v;
    }
  } else {
    // ---- wpack ----
    const int id = (blockIdx.y * 64 + blockIdx.x) * 256 + t;  // 0..65535
#pragma unroll
    for (int tap = 0; tap < 10; ++tap) {
      float v = (tap < 9) ? wd3[(size_t)id * 9 + tap] : wd1[id];
      Wp[(size_t)tap * (CC * CC) + id] = (unsigned short)f2bf(v);
    }
#pragma unroll
    for (int j = 0; j < 3; ++j) {
      int e = id + j * 65536;
      if (e < 2 * 320 * 256) {
        int inp = e / (320 * 256), rem = e % (320 * 256);
        int o = rem >> 8, c = rem & 255;
        float v;
        if (inp == 0)
          v = (o < 32) ? wq1[o * 256 + c] * LOG2E
              : (o < 64) ? wk1[(o - 32) * 256 + c] : wv1[(o - 64) * 256 + c];
        else
          v = (o < 32) ? wq2[o * 256 + c] * LOG2E
              : (o < 64) ? wk2[(o - 32) * 256 + c] : wv2[(o - 64) * 256 + c];
        Wqkv[e] = (unsigned short)f2bf(v);
      }
    }
    if (id < 640) {
      int inp = id / 320, o = id % 320;
      float v;
      if (inp == 0) v = (o < 32) ? bq1[o] * LOG2E
                        : (o < 64) ? bk1[o - 32] : bv1[o - 64];
      else          v = (o < 32) ? bq2[o] * LOG2E
                        : (o < 64) ? bk2[o - 32] : bv2[o - 64];
      Bias[id] = v;
    }
  }
}

// ---------------------------------------------------------------------------
// Kernel 1: MFMA projections. GEMM: [64 pix] x [320 o] x [K=256 c] per block.
// ---------------------------------------------------------------------------
__global__ __launch_bounds__(256) void proj_mfma_kernel(
    const unsigned short* __restrict__ Xp, const unsigned short* __restrict__ Wqkv,
    const float* __restrict__ Bias,
    unsigned short* __restrict__ Qp1, unsigned short* __restrict__ Kp1,
    unsigned short* __restrict__ Vp1,
    unsigned short* __restrict__ Qp2, unsigned short* __restrict__ Kp2,
    unsigned short* __restrict__ Vp2) {
  const int t = threadIdx.x;
  const int w = t >> 6, lane = t & 63;
  const int l15 = lane & 15, g = lane >> 4;
  const int img = blockIdx.x, pb = blockIdx.y;
  const int pix0 = pb * 64;
  const int inp = img >> 2, b = img & 3;
  const unsigned short* Xi = Xp + (size_t)img * NN * CC;
  const unsigned short* Wb = Wqkv + (size_t)inp * 320 * CC;
  const float* Bi = Bias + inp * 320;
  unsigned short* Qp = (inp ? Qp2 : Qp1) + (size_t)b * NN * CKD;
  unsigned short* Kp = (inp ? Kp2 : Kp1) + (size_t)b * NN * CKD;
  unsigned short* Vp = (inp ? Vp2 : Vp1) + (size_t)b * NN * CC;

  __shared__ unsigned short tile[320][72];   // [o][pix]

  floatx4 acc[4][5];
#pragma unroll
  for (int mf = 0; mf < 4; ++mf)
#pragma unroll
    for (int nf = 0; nf < 5; ++nf) acc[mf][nf] = (floatx4){0.f, 0.f, 0.f, 0.f};
  const int o0w = w * 80;

#pragma unroll
  for (int cb = 0; cb < 8; ++cb) {
    short8 a[4], bfr[5];
#pragma unroll
    for (int mf = 0; mf < 4; ++mf)
      a[mf] = *(const short8*)(Xi + (size_t)(pix0 + mf * 16 + l15) * CC + cb * 32 + g * 8);
#pragma unroll
    for (int nf = 0; nf < 5; ++nf)
      bfr[nf] = *(const short8*)(Wb + (size_t)(o0w + nf * 16 + l15) * CC + cb * 32 + g * 8);
#pragma unroll
    for (int nf = 0; nf < 5; ++nf)
#pragma unroll
      for (int mf = 0; mf < 4; ++mf)
        acc[mf][nf] = __builtin_amdgcn_mfma_f32_16x16x32_bf16(
            a[mf], bfr[nf], acc[mf][nf], 0, 0, 0);
  }

#pragma unroll
  for (int nf = 0; nf < 5; ++nf) {
    float bs = Bi[o0w + nf * 16 + l15];
#pragma unroll
    for (int mf = 0; mf < 4; ++mf) {
      uint2 pk;
      pk.x = f2bf(acc[mf][nf][0] + bs) | (f2bf(acc[mf][nf][1] + bs) << 16);
      pk.y = f2bf(acc[mf][nf][2] + bs) | (f2bf(acc[mf][nf][3] + bs) << 16);
      *(uint2*)&tile[o0w + nf * 16 + l15][mf * 16 + g * 4] = pk;
    }
  }
  __syncthreads();

  {
    const int pix = t >> 2, ch = t & 3;
    short8 vq, vk;
#pragma unroll
    for (int e = 0; e < 8; ++e) {
      vq[e] = (short)tile[ch * 8 + e][pix];
      vk[e] = (short)tile[32 + ch * 8 + e][pix];
    }
    *(short8*)(Qp + (size_t)(pix0 + pix) * CKD + ch * 8) = vq;
    *(short8*)(Kp + (size_t)(pix0 + pix) * CKD + ch * 8) = vk;
  }
#pragma unroll
  for (int it = 0; it < 8; ++it) {
    short8 vv = *(const short8*)&tile[64 + t][it * 8];
    *(short8*)(Vp + ((size_t)((pix0 >> 3) + it) * CC + t) * 8) = vv;
  }
}

// ---------------------------------------------------------------------------
// Kernel 2: fused flash attention + conv + epilogue.
// grid (2 att, 4 b, 64 yblk), 256 thr, 2 blocks/CU.
// Phase B: pipelined j-loop, 4 P buffers, ONE bar_lds per 2 tiles.
//   NEW (R8): all 16 GEMM2 A-frag ds_read_b128 are hoisted to region top
//   (slots jt,jt+1 complete; GEMM1 writes slots jt+2,jt+3 - disjoint), so
//   GEMM2 is pure-register MFMA, wrapped in s_setprio (T5: the 2 co-resident
//   blocks are barrier-independent -> priority arbitration has a target).
// Then: l-reduce, seed acc *= 1/l, conv accumulates into acc, epilogue.
// ---------------------------------------------------------------------------
__global__ __launch_bounds__(256, 2) void attn_kernel(
    const unsigned short* __restrict__ Qp1, const unsigned short* __restrict__ Kp1,
    const unsigned short* __restrict__ Qp2, const unsigned short* __restrict__ Kp2,
    const unsigned short* __restrict__ Vp1, const unsigned short* __restrict__ Vp2,
    const unsigned short* __restrict__ Xp, const unsigned short* __restrict__ Wp,
    const float* __restrict__ bd1, const float* __restrict__ bd3,
    const float* __restrict__ x1, const float* __restrict__ x2,
    const float* __restrict__ g1, const float* __restrict__ g2,
    float* __restrict__ out) {
  const int t = threadIdx.x;
  const int w = t >> 6, lane = t & 63;
  const int l15 = lane & 15, g = lane >> 4;
  const int att = blockIdx.x, b = blockIdx.y;
  const int yblk = blockIdx.z;
  const int i0 = yblk * 64;

  const unsigned short *Qp, *Kp, *Vp; const float *x; float gamma; float* o;
  if (att == 0) { Qp = Qp1; Kp = Kp2; Vp = Vp2; x = x1; gamma = g1[0]; o = out; }
  else          { Qp = Qp2; Kp = Kp1; Vp = Vp1; x = x2; gamma = g2[0];
                  o = out + (size_t)BB * CC * NN; }
  Qp += (size_t)b * NN * CKD; Kp += (size_t)b * NN * CKD; Vp += (size_t)b * NN * CC;
  x += (size_t)b * CC * NN; o += (size_t)b * CC * NN;
  const unsigned short* Xi = Xp + (size_t)(att * 4 + b) * NN * CC;  // own image

  __shared__ union {
    unsigned short ps[4][64][72];   // attn P 4-buf (Phase B)
    unsigned short xs[3][66][72];   // conv pixel tile (Phase C)
  } u;
  __shared__ float l_s[64];

  // Q B-frag (held whole kernel); Q is pre-scaled by log2e
  short8 bq = *(const short8*)(Qp + (size_t)(i0 + w * 16 + l15) * CKD + g * 8);

  floatx4 acc[4][4];
#pragma unroll
  for (int a = 0; a < 4; ++a)
#pragma unroll
    for (int c = 0; c < 4; ++c) acc[a][c] = (floatx4){0.f, 0.f, 0.f, 0.f};
  float l_acc = 0.f;
  const floatx4 zinit = {-EXPSHIFT, -EXPSHIFT, -EXPSHIFT, -EXPSHIFT};

  short8 kr[2][4], vr[2][8];
  auto LOADK = [&](int tt, short8* d) {
    const unsigned short* kb = Kp + ((size_t)tt * 64 + l15) * CKD + g * 8;
#pragma unroll
    for (int js = 0; js < 4; ++js) d[js] = *(const short8*)(kb + js * 16 * CKD);
  };
  auto LOADV = [&](int tt, short8* d) {
#pragma unroll
    for (int ks = 0; ks < 2; ++ks)
#pragma unroll
      for (int cs = 0; cs < 4; ++cs)
        d[ks * 4 + cs] = *(const short8*)(Vp +
            (((size_t)tt * 8 + ks * 4 + g) * CC + (w * 64 + cs * 16 + l15)) * 8);
  };
  auto GEMM1 = [&](const short8* kb, unsigned short (*psb)[72]) {
#pragma unroll
    for (int js = 0; js < 4; ++js) {
      floatx4 s = __builtin_amdgcn_mfma_f32_16x16x32_bf16(kb[js], bq, zinit, 0, 0, 0);
      float p0 = fast_exp2(s[0]);
      float p1 = fast_exp2(s[1]);
      float p2 = fast_exp2(s[2]);
      float p3 = fast_exp2(s[3]);
      l_acc += (p0 + p1) + (p2 + p3);
      unsigned u0 = __float_as_uint(p0) + 0x8000u;
      unsigned u1 = __float_as_uint(p1) + 0x8000u;
      unsigned u2 = __float_as_uint(p2) + 0x8000u;
      unsigned u3 = __float_as_uint(p3) + 0x8000u;
      uint2 pk;
      pk.x = __builtin_amdgcn_perm(u1, u0, 0x07060302u);
      pk.y = __builtin_amdgcn_perm(u3, u2, 0x07060302u);
      *(uint2*)&psb[w * 16 + l15][js * 16 + g * 4] = pk;
    }
  };
  // GEMM2 on preloaded register P-frags (pa_[ks*4+isub])
  auto GEMM2R = [&](const short8* vb, const short8* pa_) {
    __builtin_amdgcn_s_setprio(1);
#pragma unroll
    for (int ks = 0; ks < 2; ++ks)
#pragma unroll
      for (int cs = 0; cs < 4; ++cs)
#pragma unroll
        for (int isub = 0; isub < 4; ++isub)
          acc[isub][cs] = __builtin_amdgcn_mfma_f32_16x16x32_bf16(
              pa_[ks * 4 + isub], vb[ks * 4 + cs], acc[isub][cs], 0, 0, 0);
    __builtin_amdgcn_s_setprio(0);
  };

  // ================= Phase B: pipelined j-loop (2 tiles / barrier) ==========
  LOADK(0, kr[0]); LOADK(1, kr[1]);
  LOADV(0, vr[0]); LOADV(1, vr[1]);
  GEMM1(kr[0], u.ps[0]);
  GEMM1(kr[1], u.ps[1]);
  LOADK(2, kr[0]); LOADK(3, kr[1]);
  bar_lds();

  for (int jt = 0; jt < 64; jt += 2) {
    // Preload P-frags for tiles jt, jt+1 (slots jt&3,(jt+1)&3; GEMM1 below
    // writes slots (jt+2)&3,(jt+3)&3 - disjoint, so no intra-region hazard).
    short8 pa0[8], pa1[8];
#pragma unroll
    for (int ks = 0; ks < 2; ++ks)
#pragma unroll
      for (int isub = 0; isub < 4; ++isub) {
        pa0[ks * 4 + isub] =
            *(const short8*)&u.ps[jt & 3][isub * 16 + l15][ks * 32 + g * 8];
        pa1[ks * 4 + isub] =
            *(const short8*)&u.ps[(jt + 1) & 3][isub * 16 + l15][ks * 32 + g * 8];
      }
    if (jt + 2 < 64) {
      GEMM1(kr[0], u.ps[(jt + 2) & 3]);            // P(jt+2)
      if (jt + 4 < 64) LOADK(jt + 4, kr[0]);
    }
    GEMM2R(vr[0], pa0);                            // consume V(jt), P(jt)
    if (jt + 2 < 64) LOADV(jt + 2, vr[0]);
    if (jt + 3 < 64) {
      GEMM1(kr[1], u.ps[(jt + 3) & 3]);            // P(jt+3)
      if (jt + 5 < 64) LOADK(jt + 5, kr[1]);
    }
    GEMM2R(vr[1], pa1);                            // consume V(jt+1), P(jt+1)
    if (jt + 3 < 64) LOADV(jt + 3, vr[1]);
    if (jt + 2 < 64) bar_lds();
  }

  // l: reduce across g (lane bits 4,5)
  l_acc += __shfl_xor(l_acc, 16);
  l_acc += __shfl_xor(l_acc, 32);
  if (g == 0) l_s[w * 16 + l15] = l_acc;
  bar_lds();   // also: all ps reads complete -> xs overwrite safe

  // seed: acc *= 1/l  (conv then accumulates on top in the same layout)
#pragma unroll
  for (int isub = 0; isub < 4; ++isub) {
    float linv[4];
#pragma unroll
    for (int r = 0; r < 4; ++r) linv[r] = 1.f / l_s[isub * 16 + g * 4 + r];
#pragma unroll
    for (int cs = 0; cs < 4; ++cs)
#pragma unroll
      for (int r = 0; r < 4; ++r) acc[isub][cs][r] *= linv[r];
  }

  // ================= Phase C: conv accumulating into acc ================
  for (int cb = 0; cb < 4; ++cb) {
    const int c0 = cb * 64;
    if (cb) bar_lds();   // prior tap reads of xs complete
#pragma unroll
    for (int it = 0; it < 7; ++it) {
      int id = it * 256 + t;
      if (id < 1584) {                    // 3*66*8 16B-chunks
        int r = id / 528, rem = id % 528;
        int col = rem >> 3, cc = rem & 7;
        int y = yblk - 1 + r, xx = col - 1;
        short8 v = {0, 0, 0, 0, 0, 0, 0, 0};
        if (y >= 0 && y < HH && xx >= 0 && xx < WW)
          v = *(const short8*)(Xi + (size_t)(y * WW + xx) * CC + c0 + cc * 8);
        *(short8*)&u.xs[r][col][cc * 8] = v;
      }
    }
    bar_lds();
#pragma unroll
    for (int tap = 0; tap < 10; ++tap) {
      const int dy = (tap < 9) ? tap / 3 - 1 : 0;
      const int dx = (tap < 9) ? tap % 3 - 1 : 0;
      const unsigned short* wrow =
          Wp + ((size_t)tap * CC + w * 64 + l15) * CC + c0 + g * 8;
#pragma unroll
      for (int ks = 0; ks < 2; ++ks) {
        short8 af[4], bw[4];
#pragma unroll
        for (int pm = 0; pm < 4; ++pm)
          af[pm] = *(const short8*)&u.xs[1 + dy][1 + pm * 16 + l15 + dx][ks * 32 + g * 8];
#pragma unroll
        for (int on = 0; on < 4; ++on)
          bw[on] = *(const short8*)(wrow + (size_t)(on * 16) * CC + ks * 32);
#pragma unroll
        for (int pm = 0; pm < 4; ++pm)
#pragma unroll
          for (int on = 0; on < 4; ++on)
            acc[pm][on] = __builtin_amdgcn_mfma_f32_16x16x32_bf16(
                af[pm], bw[on], acc[pm][on], 0, 0, 0);
      }
    }
  }

  // epilogue: out[c][i] = x + gamma*(acc + bias)   (acc = attn/l + conv)
#pragma unroll
  for (int isub = 0; isub < 4; ++isub) {
#pragma unroll
    for (int cs = 0; cs < 4; ++cs) {
      int c = w * 64 + cs * 16 + l15;
      float bs = bd1[c] + bd3[c];
      size_t base = (size_t)c * NN + i0 + isub * 16 + g * 4;
      float4 xr = *(const float4*)(x + base);
      float4 ov;
      ov.x = xr.x + gamma * (acc[isub][cs][0] + bs);
      ov.y = xr.y + gamma * (acc[isub][cs][1] + bs);
      ov.z = xr.z + gamma * (acc[isub][cs][2] + bs);
      ov.w = xr.w + gamma * (acc[isub][cs][3] + bs);
      *(float4*)(o + base) = ov;
    }
  }
}

// ---------------------------------------------------------------------------
extern "C" void kernel_launch(void* const* d_in, const int* in_sizes, int n_in,
                              void* d_out, int out_size, void* d_ws, size_t ws_size,
                              hipStream_t stream) {
  const float* x1  = (const float*)d_in[0];
  const float* x2  = (const float*)d_in[1];
  const float* wq1 = (const float*)d_in[2];
  const float* bq1 = (const float*)d_in[3];
  const float* wk1 = (const float*)d_in[4];
  const float* bk1 = (const float*)d_in[5];
  const float* wv1 = (const float*)d_in[6];
  const float* bv1 = (const float*)d_in[7];
  const float* wq2 = (const float*)d_in[8];
  const float* bq2 = (const float*)d_in[9];
  const float* wk2 = (const float*)d_in[10];
  const float* bk2 = (const float*)d_in[11];
  const float* wv2 = (const float*)d_in[12];
  const float* bv2 = (const float*)d_in[13];
  const float* wd1 = (const float*)d_in[14];
  const float* bd1 = (const float*)d_in[15];
  const float* wd3 = (const float*)d_in[16];
  const float* bd3 = (const float*)d_in[17];
  const float* g1  = (const float*)d_in[18];
  const float* g2  = (const float*)d_in[19];
  float* out = (float*)d_out;

  // workspace layout (bytes)
  const size_t QB = (size_t)BB * NN * CKD * 2;     // 1 MB each
  const size_t VB = (size_t)BB * NN * CC * 2;      // 8 MB each
  const size_t XB = (size_t)2 * BB * NN * CC * 2;  // 16 MB
  const size_t WPB = (size_t)10 * CC * CC * 2;     // 1.31 MB
  const size_t WQB = (size_t)2 * 320 * CC * 2;     // 320 KB
  char* base = (char*)d_ws;
  unsigned short* Qp1 = (unsigned short*)(base);
  unsigned short* Kp1 = (unsigned short*)(base + QB);
  unsigned short* Qp2 = (unsigned short*)(base + 2 * QB);
  unsigned short* Kp2 = (unsigned short*)(base + 3 * QB);
  unsigned short* Vp1 = (unsigned short*)(base + 4 * QB);
  unsigned short* Vp2 = (unsigned short*)(base + 4 * QB + VB);
  unsigned short* Xp  = (unsigned short*)(base + 4 * QB + 2 * VB);
  unsigned short* Wp  = (unsigned short*)(base + 4 * QB + 2 * VB + XB);
  unsigned short* Wqkv = (unsigned short*)(base + 4 * QB + 2 * VB + XB + WPB);
  float* Bias = (float*)(base + 4 * QB + 2 * VB + XB + WPB + WQB);

  pack_kernel<<<dim3(NN / 64, CC / 64, 9), 256, 0, stream>>>(
      x1, x2, Xp, wd1, wd3, wq1, wk1, wv1, wq2, wk2, wv2,
      bq1, bk1, bv1, bq2, bk2, bv2, Wp, Wqkv, Bias);

  proj_mfma_kernel<<<dim3(2 * BB, NN / 64), 256, 0, stream>>>(
      Xp, Wqkv, Bias, Qp1, Kp1, Vp1, Qp2, Kp2, Vp2);

  attn_kernel<<<dim3(2, BB, NN / 64), 256, 0, stream>>>(
      Qp1, Kp1, Qp2, Kp2, Vp1, Vp2, Xp, Wp, bd1, bd3, x1, x2, g1, g2, out);
}

// Round 9
// 295.514 us; speedup vs baseline: 1.0764x; 1.0764x over previous
//
#include <hip/hip_runtime.h>
#include <hip/hip_bf16.h>

// Problem constants
#define CC 256      // channels
#define CKD 32      // q/k projection dim
#define NN 4096     // H*W
#define HH 64
#define WW 64
#define BB 4

#define LOG2E 1.44269504088896f
#define EXPSHIFT 23.0831203874f   // 16 * LOG2E

typedef __attribute__((ext_vector_type(8))) short short8;   // 8 bf16 (4 VGPRs)
typedef __attribute__((ext_vector_type(4))) float floatx4;  // MFMA C/D frag

__device__ __forceinline__ unsigned f2bf(float f) {
  union { float f; unsigned u; } v; v.f = f;
  unsigned r = v.u + 0x7fffu + ((v.u >> 16) & 1u);   // RNE
  return r >> 16;
}
__device__ __forceinline__ float fast_exp2(float x) {
#if __has_builtin(__builtin_amdgcn_exp2f)
  return __builtin_amdgcn_exp2f(x);
#else
  return __expf(x * 0.693147181f);
#endif
}
__device__ __forceinline__ float bf_lo(unsigned u) { return __uint_as_float(u << 16); }
__device__ __forceinline__ float bf_hi(unsigned u) { return __uint_as_float(u & 0xffff0000u); }

// LDS-only barrier: orders DS ops across waves WITHOUT draining vmcnt.
__device__ __forceinline__ void bar_lds() {
  asm volatile("s_waitcnt lgkmcnt(0)" ::: "memory");
  __builtin_amdgcn_s_barrier();
}

// ---------------------------------------------------------------------------
// Kernel 0: merged pack. z<8: pack x (fp32 [img][c][n]) -> Xp (bf16 [img][n][c]).
// z==8: pack conv weights Wp[tap][o][c] (tap 9 = 1x1), QKV weights
// Wqkv[inp][o=320][c] (q rows scaled by log2e), Bias[inp][320] (fp32).
// ---------------------------------------------------------------------------
__global__ __launch_bounds__(256) void pack_kernel(
    const float* __restrict__ x1, const float* __restrict__ x2,
    unsigned short* __restrict__ Xp,
    const float* __restrict__ wd1, const float* __restrict__ wd3,
    const float* __restrict__ wq1, const float* __restrict__ wk1,
    const float* __restrict__ wv1,
    const float* __restrict__ wq2, const float* __restrict__ wk2,
    const float* __restrict__ wv2,
    const float* __restrict__ bq1, const float* __restrict__ bk1,
    const float* __restrict__ bv1,
    const float* __restrict__ bq2, const float* __restrict__ bk2,
    const float* __restrict__ bv2,
    unsigned short* __restrict__ Wp, unsigned short* __restrict__ Wqkv,
    float* __restrict__ Bias) {
  const int t = threadIdx.x;
  __shared__ float tile[64][65];
  if (blockIdx.z < 8) {
    // ---- xpack ----
    const int nb = blockIdx.x, cbk = blockIdx.y, img = blockIdx.z;
    const float* X = ((img >> 2) ? x2 : x1) + (size_t)(img & 3) * CC * NN;
    const int n0 = nb * 64, c0 = cbk * 64;
    const int nl = t & 63, cl0 = t >> 6;
#pragma unroll
    for (int i = 0; i < 16; ++i)
      tile[cl0 + i * 4][nl] = X[(size_t)(c0 + cl0 + i * 4) * NN + n0 + nl];
    __syncthreads();
#pragma unroll
    for (int it = 0; it < 2; ++it) {
      int id = it * 256 + t;
      int nl2 = id >> 3, cc = id & 7;
      short8 v;
#pragma unroll
      for (int j = 0; j < 8; ++j) v[j] = (short)f2bf(tile[cc * 8 + j][nl2]);
      *(short8*)(Xp + (size_t)img * NN * CC + (size_t)(n0 + nl2) * CC + c0 + cc * 8) = v;
    }
  } else {
    // ---- wpack ----
    const int id = (blockIdx.y * 64 + blockIdx.x) * 256 + t;  // 0..65535
#pragma unroll
    for (int tap = 0; tap < 10; ++tap) {
      float v = (tap < 9) ? wd3[(size_t)id * 9 + tap] : wd1[id];
      Wp[(size_t)tap * (CC * CC) + id] = (unsigned short)f2bf(v);
    }
#pragma unroll
    for (int j = 0; j < 3; ++j) {
      int e = id + j * 65536;
      if (e < 2 * 320 * 256) {
        int inp = e / (320 * 256), rem = e % (320 * 256);
        int o = rem >> 8, c = rem & 255;
        float v;
        if (inp == 0)
          v = (o < 32) ? wq1[o * 256 + c] * LOG2E
              : (o < 64) ? wk1[(o - 32) * 256 + c] : wv1[(o - 64) * 256 + c];
        else
          v = (o < 32) ? wq2[o * 256 + c] * LOG2E
              : (o < 64) ? wk2[(o - 32) * 256 + c] : wv2[(o - 64) * 256 + c];
        Wqkv[e] = (unsigned short)f2bf(v);
      }
    }
    if (id < 640) {
      int inp = id / 320, o = id % 320;
      float v;
      if (inp == 0) v = (o < 32) ? bq1[o] * LOG2E
                        : (o < 64) ? bk1[o - 32] : bv1[o - 64];
      else          v = (o < 32) ? bq2[o] * LOG2E
                        : (o < 64) ? bk2[o - 32] : bv2[o - 64];
      Bias[id] = v;
    }
  }
}

// ---------------------------------------------------------------------------
// Kernel 1: MFMA projections. GEMM: [64 pix] x [320 o] x [K=256 c] per block.
// ---------------------------------------------------------------------------
__global__ __launch_bounds__(256) void proj_mfma_kernel(
    const unsigned short* __restrict__ Xp, const unsigned short* __restrict__ Wqkv,
    const float* __restrict__ Bias,
    unsigned short* __restrict__ Qp1, unsigned short* __restrict__ Kp1,
    unsigned short* __restrict__ Vp1,
    unsigned short* __restrict__ Qp2, unsigned short* __restrict__ Kp2,
    unsigned short* __restrict__ Vp2) {
  const int t = threadIdx.x;
  const int w = t >> 6, lane = t & 63;
  const int l15 = lane & 15, g = lane >> 4;
  const int img = blockIdx.x, pb = blockIdx.y;
  const int pix0 = pb * 64;
  const int inp = img >> 2, b = img & 3;
  const unsigned short* Xi = Xp + (size_t)img * NN * CC;
  const unsigned short* Wb = Wqkv + (size_t)inp * 320 * CC;
  const float* Bi = Bias + inp * 320;
  unsigned short* Qp = (inp ? Qp2 : Qp1) + (size_t)b * NN * CKD;
  unsigned short* Kp = (inp ? Kp2 : Kp1) + (size_t)b * NN * CKD;
  unsigned short* Vp = (inp ? Vp2 : Vp1) + (size_t)b * NN * CC;

  __shared__ unsigned short tile[320][72];   // [o][pix]

  floatx4 acc[4][5];
#pragma unroll
  for (int mf = 0; mf < 4; ++mf)
#pragma unroll
    for (int nf = 0; nf < 5; ++nf) acc[mf][nf] = (floatx4){0.f, 0.f, 0.f, 0.f};
  const int o0w = w * 80;

#pragma unroll
  for (int cb = 0; cb < 8; ++cb) {
    short8 a[4], bfr[5];
#pragma unroll
    for (int mf = 0; mf < 4; ++mf)
      a[mf] = *(const short8*)(Xi + (size_t)(pix0 + mf * 16 + l15) * CC + cb * 32 + g * 8);
#pragma unroll
    for (int nf = 0; nf < 5; ++nf)
      bfr[nf] = *(const short8*)(Wb + (size_t)(o0w + nf * 16 + l15) * CC + cb * 32 + g * 8);
#pragma unroll
    for (int nf = 0; nf < 5; ++nf)
#pragma unroll
      for (int mf = 0; mf < 4; ++mf)
        acc[mf][nf] = __builtin_amdgcn_mfma_f32_16x16x32_bf16(
            a[mf], bfr[nf], acc[mf][nf], 0, 0, 0);
  }

#pragma unroll
  for (int nf = 0; nf < 5; ++nf) {
    float bs = Bi[o0w + nf * 16 + l15];
#pragma unroll
    for (int mf = 0; mf < 4; ++mf) {
      uint2 pk;
      pk.x = f2bf(acc[mf][nf][0] + bs) | (f2bf(acc[mf][nf][1] + bs) << 16);
      pk.y = f2bf(acc[mf][nf][2] + bs) | (f2bf(acc[mf][nf][3] + bs) << 16);
      *(uint2*)&tile[o0w + nf * 16 + l15][mf * 16 + g * 4] = pk;
    }
  }
  __syncthreads();

  {
    const int pix = t >> 2, ch = t & 3;
    short8 vq, vk;
#pragma unroll
    for (int e = 0; e < 8; ++e) {
      vq[e] = (short)tile[ch * 8 + e][pix];
      vk[e] = (short)tile[32 + ch * 8 + e][pix];
    }
    *(short8*)(Qp + (size_t)(pix0 + pix) * CKD + ch * 8) = vq;
    *(short8*)(Kp + (size_t)(pix0 + pix) * CKD + ch * 8) = vk;
  }
#pragma unroll
  for (int it = 0; it < 8; ++it) {
    short8 vv = *(const short8*)&tile[64 + t][it * 8];
    *(short8*)(Vp + ((size_t)((pix0 >> 3) + it) * CC + t) * 8) = vv;
  }
}

// ---------------------------------------------------------------------------
// Kernel 2: fused flash attention + conv + epilogue.  (R7 structure + T5)
// grid (2 att, 4 b, 64 yblk), 256 thr, 2 blocks/CU.
// Phase B: pipelined j-loop, 4 P buffers, ONE bar_lds per 2 tiles. GEMM2
//   reads P-frags from LDS (NO register preload - R8 showed it spills) and
//   wraps its MFMA cluster in s_setprio(1/0): the 2 co-resident blocks are
//   barrier-independent, so priority arbitration has a target (T5/m191).
// Then: l-reduce, seed acc *= 1/l, conv accumulates into acc, epilogue.
// ---------------------------------------------------------------------------
__global__ __launch_bounds__(256, 2) void attn_kernel(
    const unsigned short* __restrict__ Qp1, const unsigned short* __restrict__ Kp1,
    const unsigned short* __restrict__ Qp2, const unsigned short* __restrict__ Kp2,
    const unsigned short* __restrict__ Vp1, const unsigned short* __restrict__ Vp2,
    const unsigned short* __restrict__ Xp, const unsigned short* __restrict__ Wp,
    const float* __restrict__ bd1, const float* __restrict__ bd3,
    const float* __restrict__ x1, const float* __restrict__ x2,
    const float* __restrict__ g1, const float* __restrict__ g2,
    float* __restrict__ out) {
  const int t = threadIdx.x;
  const int w = t >> 6, lane = t & 63;
  const int l15 = lane & 15, g = lane >> 4;
  const int att = blockIdx.x, b = blockIdx.y;
  const int yblk = blockIdx.z;
  const int i0 = yblk * 64;

  const unsigned short *Qp, *Kp, *Vp; const float *x; float gamma; float* o;
  if (att == 0) { Qp = Qp1; Kp = Kp2; Vp = Vp2; x = x1; gamma = g1[0]; o = out; }
  else          { Qp = Qp2; Kp = Kp1; Vp = Vp1; x = x2; gamma = g2[0];
                  o = out + (size_t)BB * CC * NN; }
  Qp += (size_t)b * NN * CKD; Kp += (size_t)b * NN * CKD; Vp += (size_t)b * NN * CC;
  x += (size_t)b * CC * NN; o += (size_t)b * CC * NN;
  const unsigned short* Xi = Xp + (size_t)(att * 4 + b) * NN * CC;  // own image

  __shared__ union {
    unsigned short ps[4][64][72];   // attn P 4-buf (Phase B)
    unsigned short xs[3][66][72];   // conv pixel tile (Phase C)
  } u;
  __shared__ float l_s[64];

  // Q B-frag (held whole kernel); Q is pre-scaled by log2e
  short8 bq = *(const short8*)(Qp + (size_t)(i0 + w * 16 + l15) * CKD + g * 8);

  floatx4 acc[4][4];
#pragma unroll
  for (int a = 0; a < 4; ++a)
#pragma unroll
    for (int c = 0; c < 4; ++c) acc[a][c] = (floatx4){0.f, 0.f, 0.f, 0.f};
  float l_acc = 0.f;
  const floatx4 zinit = {-EXPSHIFT, -EXPSHIFT, -EXPSHIFT, -EXPSHIFT};

  short8 kr[2][4], vr[2][8];
  auto LOADK = [&](int tt, short8* d) {
    const unsigned short* kb = Kp + ((size_t)tt * 64 + l15) * CKD + g * 8;
#pragma unroll
    for (int js = 0; js < 4; ++js) d[js] = *(const short8*)(kb + js * 16 * CKD);
  };
  auto LOADV = [&](int tt, short8* d) {
#pragma unroll
    for (int ks = 0; ks < 2; ++ks)
#pragma unroll
      for (int cs = 0; cs < 4; ++cs)
        d[ks * 4 + cs] = *(const short8*)(Vp +
            (((size_t)tt * 8 + ks * 4 + g) * CC + (w * 64 + cs * 16 + l15)) * 8);
  };
  auto GEMM1 = [&](const short8* kb, unsigned short (*psb)[72]) {
#pragma unroll
    for (int js = 0; js < 4; ++js) {
      floatx4 s = __builtin_amdgcn_mfma_f32_16x16x32_bf16(kb[js], bq, zinit, 0, 0, 0);
      float p0 = fast_exp2(s[0]);
      float p1 = fast_exp2(s[1]);
      float p2 = fast_exp2(s[2]);
      float p3 = fast_exp2(s[3]);
      l_acc += (p0 + p1) + (p2 + p3);
      unsigned u0 = __float_as_uint(p0) + 0x8000u;
      unsigned u1 = __float_as_uint(p1) + 0x8000u;
      unsigned u2 = __float_as_uint(p2) + 0x8000u;
      unsigned u3 = __float_as_uint(p3) + 0x8000u;
      uint2 pk;
      pk.x = __builtin_amdgcn_perm(u1, u0, 0x07060302u);
      pk.y = __builtin_amdgcn_perm(u3, u2, 0x07060302u);
      *(uint2*)&psb[w * 16 + l15][js * 16 + g * 4] = pk;
    }
  };
  auto GEMM2 = [&](const short8* vb, unsigned short (*psb)[72]) {
#pragma unroll
    for (int ks = 0; ks < 2; ++ks) {
      short8 ap[4];
#pragma unroll
      for (int isub = 0; isub < 4; ++isub)
        ap[isub] = *(const short8*)&psb[isub * 16 + l15][ks * 32 + g * 8];
      __builtin_amdgcn_s_setprio(1);
#pragma unroll
      for (int cs = 0; cs < 4; ++cs)
#pragma unroll
        for (int isub = 0; isub < 4; ++isub)
          acc[isub][cs] = __builtin_amdgcn_mfma_f32_16x16x32_bf16(
              ap[isub], vb[ks * 4 + cs], acc[isub][cs], 0, 0, 0);
      __builtin_amdgcn_s_setprio(0);
    }
  };

  // ================= Phase B: pipelined j-loop (2 tiles / barrier) ==========
  LOADK(0, kr[0]); LOADK(1, kr[1]);
  LOADV(0, vr[0]); LOADV(1, vr[1]);
  GEMM1(kr[0], u.ps[0]);
  GEMM1(kr[1], u.ps[1]);
  LOADK(2, kr[0]); LOADK(3, kr[1]);
  bar_lds();

  for (int jt = 0; jt < 64; jt += 2) {
    if (jt + 2 < 64) {
      GEMM1(kr[0], u.ps[(jt + 2) & 3]);            // P(jt+2)
      if (jt + 4 < 64) LOADK(jt + 4, kr[0]);
    }
    GEMM2(vr[0], u.ps[jt & 3]);                    // consume V(jt), P(jt)
    if (jt + 2 < 64) LOADV(jt + 2, vr[0]);
    if (jt + 3 < 64) {
      GEMM1(kr[1], u.ps[(jt + 3) & 3]);            // P(jt+3)
      if (jt + 5 < 64) LOADK(jt + 5, kr[1]);
    }
    GEMM2(vr[1], u.ps[(jt + 1) & 3]);              // consume V(jt+1), P(jt+1)
    if (jt + 3 < 64) LOADV(jt + 3, vr[1]);
    if (jt + 2 < 64) bar_lds();
  }

  // l: reduce across g (lane bits 4,5)
  l_acc += __shfl_xor(l_acc, 16);
  l_acc += __shfl_xor(l_acc, 32);
  if (g == 0) l_s[w * 16 + l15] = l_acc;
  bar_lds();   // also: all ps reads complete -> xs overwrite safe

  // seed: acc *= 1/l  (conv then accumulates on top in the same layout)
#pragma unroll
  for (int isub = 0; isub < 4; ++isub) {
    float linv[4];
#pragma unroll
    for (int r = 0; r < 4; ++r) linv[r] = 1.f / l_s[isub * 16 + g * 4 + r];
#pragma unroll
    for (int cs = 0; cs < 4; ++cs)
#pragma unroll
      for (int r = 0; r < 4; ++r) acc[isub][cs][r] *= linv[r];
  }

  // ================= Phase C: conv accumulating into acc ================
  for (int cb = 0; cb < 4; ++cb) {
    const int c0 = cb * 64;
    if (cb) bar_lds();   // prior tap reads of xs complete
#pragma unroll
    for (int it = 0; it < 7; ++it) {
      int id = it * 256 + t;
      if (id < 1584) {                    // 3*66*8 16B-chunks
        int r = id / 528, rem = id % 528;
        int col = rem >> 3, cc = rem & 7;
        int y = yblk - 1 + r, xx = col - 1;
        short8 v = {0, 0, 0, 0, 0, 0, 0, 0};
        if (y >= 0 && y < HH && xx >= 0 && xx < WW)
          v = *(const short8*)(Xi + (size_t)(y * WW + xx) * CC + c0 + cc * 8);
        *(short8*)&u.xs[r][col][cc * 8] = v;
      }
    }
    bar_lds();
#pragma unroll
    for (int tap = 0; tap < 10; ++tap) {
      const int dy = (tap < 9) ? tap / 3 - 1 : 0;
      const int dx = (tap < 9) ? tap % 3 - 1 : 0;
      const unsigned short* wrow =
          Wp + ((size_t)tap * CC + w * 64 + l15) * CC + c0 + g * 8;
#pragma unroll
      for (int ks = 0; ks < 2; ++ks) {
        short8 af[4], bw[4];
#pragma unroll
        for (int pm = 0; pm < 4; ++pm)
          af[pm] = *(const short8*)&u.xs[1 + dy][1 + pm * 16 + l15 + dx][ks * 32 + g * 8];
#pragma unroll
        for (int on = 0; on < 4; ++on)
          bw[on] = *(const short8*)(wrow + (size_t)(on * 16) * CC + ks * 32);
#pragma unroll
        for (int pm = 0; pm < 4; ++pm)
#pragma unroll
          for (int on = 0; on < 4; ++on)
            acc[pm][on] = __builtin_amdgcn_mfma_f32_16x16x32_bf16(
                af[pm], bw[on], acc[pm][on], 0, 0, 0);
      }
    }
  }

  // epilogue: out[c][i] = x + gamma*(acc + bias)   (acc = attn/l + conv)
#pragma unroll
  for (int isub = 0; isub < 4; ++isub) {
#pragma unroll
    for (int cs = 0; cs < 4; ++cs) {
      int c = w * 64 + cs * 16 + l15;
      float bs = bd1[c] + bd3[c];
      size_t base = (size_t)c * NN + i0 + isub * 16 + g * 4;
      float4 xr = *(const float4*)(x + base);
      float4 ov;
      ov.x = xr.x + gamma * (acc[isub][cs][0] + bs);
      ov.y = xr.y + gamma * (acc[isub][cs][1] + bs);
      ov.z = xr.z + gamma * (acc[isub][cs][2] + bs);
      ov.w = xr.w + gamma * (acc[isub][cs][3] + bs);
      *(float4*)(o + base) = ov;
    }
  }
}

// ---------------------------------------------------------------------------
extern "C" void kernel_launch(void* const* d_in, const int* in_sizes, int n_in,
                              void* d_out, int out_size, void* d_ws, size_t ws_size,
                              hipStream_t stream) {
  const float* x1  = (const float*)d_in[0];
  const float* x2  = (const float*)d_in[1];
  const float* wq1 = (const float*)d_in[2];
  const float* bq1 = (const float*)d_in[3];
  const float* wk1 = (const float*)d_in[4];
  const float* bk1 = (const float*)d_in[5];
  const float* wv1 = (const float*)d_in[6];
  const float* bv1 = (const float*)d_in[7];
  const float* wq2 = (const float*)d_in[8];
  const float* bq2 = (const float*)d_in[9];
  const float* wk2 = (const float*)d_in[10];
  const float* bk2 = (const float*)d_in[11];
  const float* wv2 = (const float*)d_in[12];
  const float* bv2 = (const float*)d_in[13];
  const float* wd1 = (const float*)d_in[14];
  const float* bd1 = (const float*)d_in[15];
  const float* wd3 = (const float*)d_in[16];
  const float* bd3 = (const float*)d_in[17];
  const float* g1  = (const float*)d_in[18];
  const float* g2  = (const float*)d_in[19];
  float* out = (float*)d_out;

  // workspace layout (bytes)
  const size_t QB = (size_t)BB * NN * CKD * 2;     // 1 MB each
  const size_t VB = (size_t)BB * NN * CC * 2;      // 8 MB each
  const size_t XB = (size_t)2 * BB * NN * CC * 2;  // 16 MB
  const size_t WPB = (size_t)10 * CC * CC * 2;     // 1.31 MB
  const size_t WQB = (size_t)2 * 320 * CC * 2;     // 320 KB
  char* base = (char*)d_ws;
  unsigned short* Qp1 = (unsigned short*)(base);
  unsigned short* Kp1 = (unsigned short*)(base + QB);
  unsigned short* Qp2 = (unsigned short*)(base + 2 * QB);
  unsigned short* Kp2 = (unsigned short*)(base + 3 * QB);
  unsigned short* Vp1 = (unsigned short*)(base + 4 * QB);
  unsigned short* Vp2 = (unsigned short*)(base + 4 * QB + VB);
  unsigned short* Xp  = (unsigned short*)(base + 4 * QB + 2 * VB);
  unsigned short* Wp  = (unsigned short*)(base + 4 * QB + 2 * VB + XB);
  unsigned short* Wqkv = (unsigned short*)(base + 4 * QB + 2 * VB + XB + WPB);
  float* Bias = (float*)(base + 4 * QB + 2 * VB + XB + WPB + WQB);

  pack_kernel<<<dim3(NN / 64, CC / 64, 9), 256, 0, stream>>>(
      x1, x2, Xp, wd1, wd3, wq1, wk1, wv1, wq2, wk2, wv2,
      bq1, bk1, bv1, bq2, bk2, bv2, Wp, Wqkv, Bias);

  proj_mfma_kernel<<<dim3(2 * BB, NN / 64), 256, 0, stream>>>(
      Xp, Wqkv, Bias, Qp1, Kp1, Vp1, Qp2, Kp2, Vp2);

  attn_kernel<<<dim3(2, BB, NN / 64), 256, 0, stream>>>(
      Qp1, Kp1, Qp2, Kp2, Vp1, Vp2, Xp, Wp, bd1, bd3, x1, x2, g1, g2, out);
}